// Round 12
// baseline (62.233 us; speedup 1.0000x reference)
//
#include <hip/hip_runtime.h>

// ExponentialUnitNorm: s_t = 0.01*|x_t| + 0.99*s_{t-1};  out_t = x_t / sqrt(s_t)
// x: [B=16, C=2, T=1000, F=481, 2] fp32.  init_state: [1,1,F,1] fp32.
//
// R11: single-kernel, ONE barrier total. Block = (bc, 64-wide f-tile),
// 1024 thr = 16 waves; wave w owns rows [t0(w), t0(w)+len(w)) with
// len = 63 (w<8) / 62 (w>=8)  (8*63 + 8*62 = 1000 = all of T).
//   phase A: stream own rows, zero-init partial sum Cl -> lds_c[w][fx]
//   ONE __syncthreads()
//   phase B: chunk-init = init_state composed with lds_c[0..w-1] (<=15 fmas),
//            re-read rows (L3-hot: R10 measured FETCH=60MB << 123MB logical)
//            and apply, stream out.
// No supersteps, no carry, no atomics, no cooperative launch.
// Grid 256 blocks x 1024 thr = 16 waves/CU (2x R10's 8) for latency hiding.
// R10 post-mortem: VGPR=44 proved the compiler already re-reads x instead of
// stashing; explicit re-read makes that deterministic (no scratch-spill risk).

#define EPS_F 1e-14f

constexpr int B = 16, C = 2, T = 1000, F = 481;
constexpr int BC = B * C;        // 32
constexpr int FW = 64;           // f-tile width = one wave
constexpr int NTILE = 8;         // ceil(481/64)
constexpr int WV = 16;           // waves per block
constexpr int ROWS = F * 2;      // 962 floats per t-row

__device__ __forceinline__ int wbase(int w) {
    return (w < 8) ? 63 * w : 504 + 62 * (w - 8);
}
__device__ __forceinline__ int wlen(int w) { return (w < 8) ? 63 : 62; }

__global__ __launch_bounds__(1024, 4)
void k_fused(const float* __restrict__ x, const float* __restrict__ init_state,
             float* __restrict__ out) {
    __shared__ float lds_c[WV][FW];

    const int fx   = threadIdx.x & (FW - 1);
    const int w    = threadIdx.x >> 6;
    const int bc   = blockIdx.x & (BC - 1);
    const int tile = blockIdx.x >> 5;
    const int f    = tile * FW + fx;
    const bool act = (f < F);

    double p = 1.0;
    for (int i = 0; i < 62; ++i) p *= 0.99;
    const float A62 = (float)p;
    const float A63 = (float)(p * 0.99);

    const int t0  = wbase(w);
    const int len = wlen(w);
    const float* xp = x + ((size_t)(bc * T + t0) * F + f) * 2;

    // ---- phase A: zero-init partial sum over own rows ----
    float Cl = 0.0f;
    if (act) {
        for (int j = 0; j < len; ++j) {
            float2 v = *(const float2*)(xp + (size_t)j * ROWS);
            float m = fmaxf(fmaf(v.x, v.x, v.y * v.y), EPS_F);
            Cl = fmaf(0.99f, Cl, 0.01f * __builtin_amdgcn_sqrtf(m));
        }
    }
    lds_c[w][fx] = Cl;
    __syncthreads();  // the only barrier

    // ---- phase B: chunk-init from LDS prefix, then apply ----
    float sloc = act ? init_state[f] : 1.0f;
#pragma unroll
    for (int jw = 0; jw < WV - 1; ++jw) {
        const float aL = (jw < 8) ? A63 : A62;
        if (jw < w) sloc = fmaf(aL, sloc, lds_c[jw][fx]);
    }

    if (act) {
        float* op = out + ((size_t)(bc * T + t0) * F + f) * 2;
        for (int j = 0; j < len; ++j) {
            float2 v = *(const float2*)(xp + (size_t)j * ROWS);  // L3-hot re-read
            float m = fmaxf(fmaf(v.x, v.x, v.y * v.y), EPS_F);
            sloc = fmaf(0.99f, sloc, 0.01f * __builtin_amdgcn_sqrtf(m));
            const float inv = __builtin_amdgcn_rsqf(sloc);
            float2 o;
            o.x = v.x * inv;
            o.y = v.y * inv;
            *(float2*)(op + (size_t)j * ROWS) = o;
        }
    }
}

extern "C" void kernel_launch(void* const* d_in, const int* in_sizes, int n_in,
                              void* d_out, int out_size, void* d_ws, size_t ws_size,
                              hipStream_t stream) {
    const float* x          = (const float*)d_in[0];
    const float* init_state = (const float*)d_in[1];
    float* out = (float*)d_out;

    k_fused<<<dim3(NTILE * BC), 1024, 0, stream>>>(x, init_state, out);
}

// Round 13
// 59.056 us; speedup vs baseline: 1.0538x; 1.0538x over previous
//
#include <hip/hip_runtime.h>

// ExponentialUnitNorm: s_t = 0.01*|x_t| + 0.99*s_{t-1};  out_t = x_t / sqrt(s_t)
// x: [B=16, C=2, T=1000, F=481, 2] fp32.  init_state: [1,1,F,1] fp32.
//
// R12 = R10's superstep structure (the 45.4us winner) + 16 waves/block.
// WHY supersteps: R11 (monolithic, 1 barrier) regressed to 62us with
// FETCH=121MB — reuse distance between first read and re-read must stay
// << L3 (256MB). Superstep of 400 rows bounds it to ~100MB grid-wide ->
// re-reads are L3 hits (R10 measured FETCH=60MB << 123MB logical).
// Block = (bc, 64-wide f-tile), 1024 thr = 16 waves (16 waves/CU, 2x R10).
// Supersteps: 400/400/200 rows; wave w owns 25 rows (tail: 13 w<8 / 12 w>=8).
// Per superstep: phase A stream own rows -> partial Cl -> lds_c[w][fx];
// syncA; prefix (<=15 fmas) from lds_c + carry; syncB; w15 updates carry;
// phase B re-read rows (L3-hot) + apply + write.

#define EPS_F 1e-14f

constexpr int B = 16, C = 2, T = 1000, F = 481;
constexpr int BC = B * C;        // 32
constexpr int FW = 64;           // f-tile width
constexpr int NTILE = 8;         // ceil(481/64)
constexpr int WV = 16;           // waves per block
constexpr int RW = 25;           // rows per wave, full supersteps
constexpr int RSTEP = WV * RW;   // 400
constexpr int ROWS = F * 2;      // 962 floats per t-row

__global__ __launch_bounds__(1024)
void k_fused(const float* __restrict__ x, const float* __restrict__ init_state,
             float* __restrict__ out) {
    __shared__ float lds_c[WV][FW];
    __shared__ float carry[FW];

    const int fx   = threadIdx.x & (FW - 1);
    const int w    = threadIdx.x >> 6;
    const int bc   = blockIdx.x & (BC - 1);
    const int tile = blockIdx.x >> 5;
    const int f    = tile * FW + fx;
    const bool act = (f < F);

    double p = 1.0;
    for (int i = 0; i < 12; ++i) p *= 0.99;
    const float A12 = (float)p;
    const float A13 = (float)(p * 0.99);
    double q = 1.0;
    for (int i = 0; i < RW; ++i) q *= 0.99;
    const float A25 = (float)q;

    if (threadIdx.x < FW) carry[fx] = act ? init_state[f] : 1.0f;

    // ---- two full supersteps of 400 rows ----
    for (int s = 0; s < 2; ++s) {
        const int t0 = s * RSTEP + w * RW;
        const float* xp = x + ((size_t)(bc * T + t0) * F + f) * 2;

        float Cl = 0.0f;
        if (act) {
#pragma unroll 5
            for (int j = 0; j < RW; ++j) {
                float2 v = *(const float2*)(xp + (size_t)j * ROWS);
                float m = fmaxf(fmaf(v.x, v.x, v.y * v.y), EPS_F);
                Cl = fmaf(0.99f, Cl, 0.01f * __builtin_amdgcn_sqrtf(m));
            }
        }
        lds_c[w][fx] = Cl;
        __syncthreads();  // A: lds_c ready; carry (prev write) visible

        float sloc = carry[fx];
#pragma unroll
        for (int jw = 0; jw < WV - 1; ++jw)
            if (jw < w) sloc = fmaf(A25, sloc, lds_c[jw][fx]);
        __syncthreads();  // B: all carry/lds_c reads done

        if (w == WV - 1) carry[fx] = fmaf(A25, sloc, Cl);

        float* op = out + ((size_t)(bc * T + t0) * F + f) * 2;
        if (act) {
#pragma unroll 5
            for (int j = 0; j < RW; ++j) {
                float2 v = *(const float2*)(xp + (size_t)j * ROWS);  // L3-hot
                float m = fmaxf(fmaf(v.x, v.x, v.y * v.y), EPS_F);
                sloc = fmaf(0.99f, sloc, 0.01f * __builtin_amdgcn_sqrtf(m));
                const float inv = __builtin_amdgcn_rsqf(sloc);
                float2 o;
                o.x = v.x * inv;
                o.y = v.y * inv;
                *(float2*)(op + (size_t)j * ROWS) = o;
            }
        }
    }

    // ---- tail superstep: 200 rows; wave w owns 13 (w<8) / 12 (w>=8) ----
    {
        const int len = (w < 8) ? 13 : 12;
        const int t0  = 800 + ((w < 8) ? 13 * w : 104 + 12 * (w - 8));
        const float* xp = x + ((size_t)(bc * T + t0) * F + f) * 2;

        float Cl = 0.0f;
        if (act) {
            for (int j = 0; j < len; ++j) {
                float2 v = *(const float2*)(xp + (size_t)j * ROWS);
                float m = fmaxf(fmaf(v.x, v.x, v.y * v.y), EPS_F);
                Cl = fmaf(0.99f, Cl, 0.01f * __builtin_amdgcn_sqrtf(m));
            }
        }
        lds_c[w][fx] = Cl;
        __syncthreads();

        float sloc = carry[fx];
#pragma unroll
        for (int jw = 0; jw < WV - 1; ++jw) {
            const float aL = (jw < 8) ? A13 : A12;
            if (jw < w) sloc = fmaf(aL, sloc, lds_c[jw][fx]);
        }

        float* op = out + ((size_t)(bc * T + t0) * F + f) * 2;
        if (act) {
            for (int j = 0; j < len; ++j) {
                float2 v = *(const float2*)(xp + (size_t)j * ROWS);
                float m = fmaxf(fmaf(v.x, v.x, v.y * v.y), EPS_F);
                sloc = fmaf(0.99f, sloc, 0.01f * __builtin_amdgcn_sqrtf(m));
                const float inv = __builtin_amdgcn_rsqf(sloc);
                float2 o;
                o.x = v.x * inv;
                o.y = v.y * inv;
                *(float2*)(op + (size_t)j * ROWS) = o;
            }
        }
    }
}

extern "C" void kernel_launch(void* const* d_in, const int* in_sizes, int n_in,
                              void* d_out, int out_size, void* d_ws, size_t ws_size,
                              hipStream_t stream) {
    const float* x          = (const float*)d_in[0];
    const float* init_state = (const float*)d_in[1];
    float* out = (float*)d_out;

    k_fused<<<dim3(NTILE * BC), 1024, 0, stream>>>(x, init_state, out);
}

// Round 14
// 47.132 us; speedup vs baseline: 1.3204x; 1.2530x over previous
//
#include <hip/hip_runtime.h>

// ExponentialUnitNorm: s_t = 0.01*|x_t| + 0.99*s_{t-1};  out_t = x_t / sqrt(s_t)
// x: [B=16, C=2, T=1000, F=481, 2] fp32.  init_state: [1,1,F,1] fp32.
//
// R13: superstep scan with LDS stash — x read from HBM exactly ONCE/replay.
// R10 (45.4us) relied on L3 for the phase-B re-read (FETCH=60MB); R12 showed
// the reuse window must stay small (400-row superstep -> FETCH=116MB, 59us).
// R13 removes the L3 dependence: superstep slab (100 rows x 64 f x float2 =
// 51.2KB) lives in LDS. Block = (bc, 64-wide f-tile), 1024 thr = 16 waves;
// wave w owns 7 rows (w<4) / 6 rows (w>=4) per superstep (4*7+12*6=100).
// Per superstep:
//   A: load own rows (HBM) -> stash[] + zero-init partial Cl -> lds_c[w][fx]
//   syncthreads
//   B: chunk-init = carry[par] + prefix over lds_c (<=15 fmas);
//      w15 writes carry[par^1] (double-buffered -> no mid barrier);
//      apply from stash, write out
//   syncthreads  (WAR: next superstep overwrites stash/lds_c)
// 20 block barriers total, no atomics, no cooperative launch.
// HBM floor: 123MB read (less w/ cross-replay L3 survival) + 123MB write.

#define EPS_F 1e-14f

constexpr int B = 16, C = 2, T = 1000, F = 481;
constexpr int BC = B * C;        // 32
constexpr int FW = 64;           // f-tile width = one wave
constexpr int NTILE = 8;         // ceil(481/64)
constexpr int WV = 16;           // waves per block
constexpr int RSTEP = 100;       // rows per superstep
constexpr int NSUP = T / RSTEP;  // 10
constexpr int ROWS = F * 2;      // 962 floats per t-row
constexpr int VMAX = 7;          // max rows per wave per superstep

__device__ __forceinline__ int wbase(int w) { return (w < 4) ? 7 * w : 28 + 6 * (w - 4); }
__device__ __forceinline__ int wlen(int w)  { return (w < 4) ? 7 : 6; }

__global__ __launch_bounds__(1024)
void k_fused(const float* __restrict__ x, const float* __restrict__ init_state,
             float* __restrict__ out) {
    __shared__ float2 stash[RSTEP][FW];   // 51200 B
    __shared__ float  lds_c[WV][FW];      // 4096 B
    __shared__ float  carry[2][FW];       // 512 B

    const int fx   = threadIdx.x & (FW - 1);
    const int w    = threadIdx.x >> 6;
    const int bc   = blockIdx.x & (BC - 1);
    const int tile = blockIdx.x >> 5;
    const int f    = tile * FW + fx;
    const bool act = (f < F);

    double p = 1.0;
    for (int i = 0; i < 6; ++i) p *= 0.99;
    const float A6 = (float)p;
    const float A7 = (float)(p * 0.99);

    if (threadIdx.x < FW) carry[0][fx] = act ? init_state[f] : 1.0f;

    const int rb    = wbase(w);
    const int len   = wlen(w);
    const float aOwn = (w < 4) ? A7 : A6;

    for (int s = 0; s < NSUP; ++s) {
        const int par = s & 1;
        const int t0  = s * RSTEP + rb;
        const float* xp = x + ((size_t)(bc * T + t0) * F + f) * 2;

        // ---- phase A: HBM -> stash + zero-init partial sum ----
        float Cl = 0.0f;
#pragma unroll
        for (int j = 0; j < VMAX; ++j) {
            if (j < len) {
                float2 v = act ? *(const float2*)(xp + (size_t)j * ROWS)
                               : make_float2(0.0f, 0.0f);
                stash[rb + j][fx] = v;
                float m = fmaxf(fmaf(v.x, v.x, v.y * v.y), EPS_F);
                Cl = fmaf(0.99f, Cl, 0.01f * __builtin_amdgcn_sqrtf(m));
            }
        }
        lds_c[w][fx] = Cl;
        __syncthreads();  // A: stash + lds_c (+ step-0 carry) visible

        // ---- phase B: chunk-init, publish carry, apply from stash ----
        float sloc = carry[par][fx];
#pragma unroll
        for (int jw = 0; jw < WV - 1; ++jw) {
            const float aL = (jw < 4) ? A7 : A6;
            if (jw < w) sloc = fmaf(aL, sloc, lds_c[jw][fx]);
        }
        if (w == WV - 1) carry[par ^ 1][fx] = fmaf(aOwn, sloc, Cl);

        float* op = out + ((size_t)(bc * T + t0) * F + f) * 2;
#pragma unroll
        for (int j = 0; j < VMAX; ++j) {
            if (j < len) {
                float2 v = stash[rb + j][fx];
                float m = fmaxf(fmaf(v.x, v.x, v.y * v.y), EPS_F);
                sloc = fmaf(0.99f, sloc, 0.01f * __builtin_amdgcn_sqrtf(m));
                const float inv = __builtin_amdgcn_rsqf(sloc);
                float2 o;
                o.x = v.x * inv;
                o.y = v.y * inv;
                if (act) *(float2*)(op + (size_t)j * ROWS) = o;
            }
        }
        __syncthreads();  // end: protect stash/lds_c against next superstep
    }
}

extern "C" void kernel_launch(void* const* d_in, const int* in_sizes, int n_in,
                              void* d_out, int out_size, void* d_ws, size_t ws_size,
                              hipStream_t stream) {
    const float* x          = (const float*)d_in[0];
    const float* init_state = (const float*)d_in[1];
    float* out = (float*)d_out;

    k_fused<<<dim3(NTILE * BC), 1024, 0, stream>>>(x, init_state, out);
}